// Round 1
// baseline (2547.508 us; speedup 1.0000x reference)
//
#include <hip/hip_runtime.h>
#include <hip/hip_bf16.h>

#define ALPHA   0.3f
#define NEG_INF (-9e15f)
#define BN_EPS  1e-5f

// ---------------------------------------------------------------------------
// K1: H[51200,256] = feat[51200,768] @ Wcat[768,256]
//     Wcat[k, h*32+f] = Wh[h,k,f]   (8 heads fused as column blocks)
// f32 tiled GEMM: 64x64 tile, BK=16, 256 threads, 4x4 micro-tile.
// ---------------------------------------------------------------------------
__global__ __launch_bounds__(256) void k_gemm1(const float* __restrict__ A,
                                               const float* __restrict__ Wh,
                                               float* __restrict__ H)
{
    __shared__ float As[16][68];   // [k][m], stride 68 keeps float4 16B-aligned
    __shared__ float Bs[16][68];   // [k][n]
    const int tid = threadIdx.x;
    const int tx = tid & 15, ty = tid >> 4;
    const size_t m0 = (size_t)blockIdx.x * 64;
    const int n0 = blockIdx.y * 64;
    const int arow = tid >> 2;          // 0..63
    const int ak4  = (tid & 3) * 4;     // 0,4,8,12
    float acc[4][4] = {};

    for (int kt = 0; kt < 768; kt += 16) {
        __syncthreads();
        { // A tile: 64 rows x 16 k, one float4 per thread (coalesced)
            const float4 a4 = *(const float4*)&A[(m0 + arow) * 768 + kt + ak4];
            As[ak4+0][arow] = a4.x; As[ak4+1][arow] = a4.y;
            As[ak4+2][arow] = a4.z; As[ak4+3][arow] = a4.w;
        }
        #pragma unroll
        for (int i = 0; i < 4; ++i) { // B tile: 16 k x 64 cols
            int l = tid + 256 * i;
            int k = l >> 6, c = l & 63;
            int col = n0 + c;
            Bs[k][c] = Wh[((size_t)(col >> 5) * 768 + kt + k) * 32 + (col & 31)];
        }
        __syncthreads();
        #pragma unroll
        for (int k = 0; k < 16; ++k) {
            float4 a4 = *(const float4*)&As[k][ty * 4];
            float4 b4 = *(const float4*)&Bs[k][tx * 4];
            float av[4] = {a4.x, a4.y, a4.z, a4.w};
            float bv[4] = {b4.x, b4.y, b4.z, b4.w};
            #pragma unroll
            for (int i = 0; i < 4; ++i)
                #pragma unroll
                for (int j = 0; j < 4; ++j)
                    acc[i][j] += av[i] * bv[j];
        }
    }
    #pragma unroll
    for (int i = 0; i < 4; ++i) {
        float4 v = make_float4(acc[i][0], acc[i][1], acc[i][2], acc[i][3]);
        *(float4*)&H[(m0 + ty * 4 + i) * 256 + n0 + tx * 4] = v;
    }
}

// ---------------------------------------------------------------------------
// K2: per (b, head): s1/s2, masked-softmax attention, out = att@H, elu, BN.
// Writes x in place over H (block owns its 32-col slice; H tile cached in LDS).
// ---------------------------------------------------------------------------
__global__ __launch_bounds__(256) void k_attn1(float* __restrict__ H,
    const int* __restrict__ adj, const float* __restrict__ ah,
    const float* __restrict__ bng, const float* __restrict__ bnb,
    const float* __restrict__ bnm, const float* __restrict__ bnv)
{
    __shared__ float HsT[32][208];      // transposed head tile, 16B-aligned rows
    __shared__ float s1[200], s2[200];
    __shared__ float av[64];
    __shared__ float p[8][200];         // exp-weights for an 8-row chunk
    __shared__ float rsum[8];
    const int tid  = threadIdx.x;
    const int b    = blockIdx.x >> 3;
    const int head = blockIdx.x & 7;
    float* Hb = H + (size_t)b * 200 * 256 + head * 32;
    const int* adjb = adj + (size_t)b * 200 * 200;

    for (int idx = tid; idx < 6400; idx += 256) {
        int n = idx >> 5, f = idx & 31;
        HsT[f][n] = Hb[n * 256 + f];
    }
    if (tid < 64) av[tid] = ah[head * 64 + tid];
    __syncthreads();

    if (tid < 200) {
        float v1 = 0.f, v2 = 0.f;
        #pragma unroll
        for (int f = 0; f < 32; ++f) {
            float h = HsT[f][tid];
            v1 += h * av[f];
            v2 += h * av[32 + f];
        }
        s1[tid] = v1; s2[tid] = v2;
    }
    __syncthreads();

    const int il   = tid >> 5;   // 0..7: row within chunk (half-wave per row)
    const int lane = tid & 31;
    const int fcol = tid & 31;

    for (int i0 = 0; i0 < 200; i0 += 8) {
        const int i = i0 + il;
        // ---- step 1: masked scores, row max, exp, row sum ----
        float m = -INFINITY;
        float vbuf[7];
        const float s1i = s1[i];
        #pragma unroll
        for (int t = 0; t < 7; ++t) {
            int j = lane + 32 * t;
            float v = -INFINITY;
            if (j < 200) {
                float e = s1i + s2[j];
                e = e >= 0.f ? e : ALPHA * e;
                v = (adjb[i * 200 + j] > 0) ? e : NEG_INF;
            }
            vbuf[t] = v;
            m = fmaxf(m, v);
        }
        #pragma unroll
        for (int off = 16; off >= 1; off >>= 1) m = fmaxf(m, __shfl_xor(m, off));
        float s = 0.f;
        #pragma unroll
        for (int t = 0; t < 7; ++t) {
            int j = lane + 32 * t;
            float pe = __expf(vbuf[t] - m);   // -INF lanes -> 0
            if (j < 200) p[il][j] = pe;
            s += pe;
        }
        #pragma unroll
        for (int off = 16; off >= 1; off >>= 1) s += __shfl_xor(s, off);
        if (lane == 0) rsum[il] = s;
        __syncthreads();
        // ---- step 2: out[i][f] = (sum_j p*H[j][f]) / sum; elu; BN ----
        float acc = 0.f;
        for (int j = 0; j < 200; j += 4) {
            float4 pv = *(const float4*)&p[il][j];
            float4 hv = *(const float4*)&HsT[fcol][j];
            acc += pv.x * hv.x + pv.y * hv.y + pv.z * hv.z + pv.w * hv.w;
        }
        float o = acc / rsum[il];
        o = o > 0.f ? o : expm1f(o);                       // elu
        float inv = bng[i] * rsqrtf(bnv[i] + BN_EPS);      // BN (channel = node)
        o = (o - bnm[i]) * inv + bnb[i];
        Hb[i * 256 + fcol] = o;                            // in-place x
        __syncthreads();
    }
}

// ---------------------------------------------------------------------------
// K3: Y[51200,36] = x[51200,256] @ [W_sent | W_para | W_qt]
// ---------------------------------------------------------------------------
__global__ __launch_bounds__(256) void k_gemm2(const float* __restrict__ X,
    const float* __restrict__ Ws, const float* __restrict__ Wp,
    const float* __restrict__ Wq, float* __restrict__ Y)
{
    __shared__ float Wl[256][36];
    __shared__ float XsT[64][68];   // [k][row]
    const int tid = threadIdx.x;
    {   // stage weights (once)
        int k = tid;
        Wl[k][0] = Ws[k * 2 + 0]; Wl[k][1] = Ws[k * 2 + 1];
        Wl[k][2] = Wp[k * 2 + 0]; Wl[k][3] = Wp[k * 2 + 1];
        #pragma unroll
        for (int f = 0; f < 32; ++f) Wl[k][4 + f] = Wq[k * 32 + f];
    }
    const int r  = tid & 63;
    const int cg = tid >> 6;
    const int c0 = cg * 9;
    const size_t row0 = (size_t)blockIdx.x * 64;
    float acc[9] = {};

    for (int kt = 0; kt < 256; kt += 64) {
        __syncthreads();
        #pragma unroll
        for (int i = 0; i < 4; ++i) {      // 64x64 X tile, transposed into LDS
            int l = tid + 256 * i;
            int row = l >> 4;
            int k4 = (l & 15) * 4;
            const float4 x4 = *(const float4*)&X[(row0 + row) * 256 + kt + k4];
            XsT[k4 + 0][row] = x4.x; XsT[k4 + 1][row] = x4.y;
            XsT[k4 + 2][row] = x4.z; XsT[k4 + 3][row] = x4.w;
        }
        __syncthreads();
        for (int k = 0; k < 64; ++k) {
            float xv = XsT[k][r];
            #pragma unroll
            for (int c = 0; c < 9; ++c)
                acc[c] += xv * Wl[kt + k][c0 + c];
        }
    }
    float* yr = Y + (row0 + r) * 36 + c0;
    #pragma unroll
    for (int c = 0; c < 9; ++c) yr[c] = acc[c];
}

// ---------------------------------------------------------------------------
// K4: per b: 2nd-layer attention for sent (+sigmoid) and para (+elu) on all
// rows, and qt (row 0 only) -> elu(h_qt @ W2).
// ---------------------------------------------------------------------------
__global__ __launch_bounds__(256) void k_attn2(const float* __restrict__ Y,
    const int* __restrict__ adj, const float* __restrict__ a_s,
    const float* __restrict__ a_p, const float* __restrict__ a_q,
    const float* __restrict__ W2, float* __restrict__ out)
{
    __shared__ float Ys[200][37];
    __shared__ float s1s[200], s2s[200], p1s[200], p2s[200], sq2[200];
    __shared__ float p0[200];
    __shared__ float hqt[32];
    __shared__ float sumq_s;
    __shared__ float asl[4], apl[4], aql[64], w2l[64];
    const int tid = threadIdx.x;
    const int b   = blockIdx.x;
    const float* Yb = Y + (size_t)b * 7200;
    const int* adjb = adj + (size_t)b * 200 * 200;

    for (int idx = tid; idx < 7200; idx += 256) {
        int j = idx / 36;
        int c = idx - j * 36;
        Ys[j][c] = Yb[idx];
    }
    if (tid < 4)  { asl[tid] = a_s[tid]; apl[tid] = a_p[tid]; }
    if (tid < 64) { aql[tid] = a_q[tid]; w2l[tid] = W2[tid]; }
    __syncthreads();

    if (tid < 200) {
        int j = tid;
        s1s[j] = Ys[j][0] * asl[0] + Ys[j][1] * asl[1];
        s2s[j] = Ys[j][0] * asl[2] + Ys[j][1] * asl[3];
        p1s[j] = Ys[j][2] * apl[0] + Ys[j][3] * apl[1];
        p2s[j] = Ys[j][2] * apl[2] + Ys[j][3] * apl[3];
        float a = 0.f;
        #pragma unroll
        for (int f = 0; f < 32; ++f) a += Ys[j][4 + f] * aql[32 + f];
        sq2[j] = a;
    }
    __syncthreads();

    const int w = tid >> 6, lane = tid & 63;
    for (int i = w; i < 200; i += 4) {   // one wave per row
        const float s1i = s1s[i], p1i = p1s[i];
        float ms = -INFINITY, mp = -INFINITY;
        float es[4], ep[4];
        #pragma unroll
        for (int t = 0; t < 4; ++t) {
            int j = lane + 64 * t;
            int jj = j < 200 ? j : 0;
            int a = (j < 200) ? adjb[i * 200 + j] : 0;
            float e1 = s1i + s2s[jj]; e1 = e1 >= 0.f ? e1 : ALPHA * e1;
            float e2 = p1i + p2s[jj]; e2 = e2 >= 0.f ? e2 : ALPHA * e2;
            es[t] = (a > 0) ? e1 : (j < 200 ? NEG_INF : -INFINITY);
            ep[t] = (a > 0) ? e2 : (j < 200 ? NEG_INF : -INFINITY);
            ms = fmaxf(ms, es[t]); mp = fmaxf(mp, ep[t]);
        }
        #pragma unroll
        for (int off = 32; off >= 1; off >>= 1) {
            ms = fmaxf(ms, __shfl_xor(ms, off));
            mp = fmaxf(mp, __shfl_xor(mp, off));
        }
        float ss = 0.f, sp = 0.f, os0 = 0.f, os1 = 0.f, op0 = 0.f, op1 = 0.f;
        #pragma unroll
        for (int t = 0; t < 4; ++t) {
            int j = lane + 64 * t;
            int jj = j < 200 ? j : 0;
            float pes = __expf(es[t] - ms);
            float pep = __expf(ep[t] - mp);
            ss += pes; sp += pep;
            os0 += pes * Ys[jj][0]; os1 += pes * Ys[jj][1];
            op0 += pep * Ys[jj][2]; op1 += pep * Ys[jj][3];
        }
        #pragma unroll
        for (int off = 32; off >= 1; off >>= 1) {
            ss  += __shfl_xor(ss, off);  sp  += __shfl_xor(sp, off);
            os0 += __shfl_xor(os0, off); os1 += __shfl_xor(os1, off);
            op0 += __shfl_xor(op0, off); op1 += __shfl_xor(op1, off);
        }
        if (lane == 0) {
            float v0 = os0 / ss, v1 = os1 / ss;
            out[((size_t)b * 200 + i) * 2 + 0] = 1.f / (1.f + __expf(-v0));
            out[((size_t)b * 200 + i) * 2 + 1] = 1.f / (1.f + __expf(-v1));
            float q0 = op0 / sp, q1 = op1 / sp;
            out[102400 + ((size_t)b * 200 + i) * 2 + 0] = q0 > 0.f ? q0 : expm1f(q0);
            out[102400 + ((size_t)b * 200 + i) * 2 + 1] = q1 > 0.f ? q1 : expm1f(q1);
        }
    }

    // ---- qtype head: attention row 0 only ----
    if (tid < 64) {
        float s1q = 0.f;
        #pragma unroll
        for (int f = 0; f < 32; ++f) s1q += Ys[0][4 + f] * aql[f];
        float mq = -INFINITY;
        float eq[4];
        #pragma unroll
        for (int t = 0; t < 4; ++t) {
            int j = tid + 64 * t;
            int jj = j < 200 ? j : 0;
            int a = (j < 200) ? adjb[j] : 0;
            float e = s1q + sq2[jj]; e = e >= 0.f ? e : ALPHA * e;
            eq[t] = (a > 0) ? e : (j < 200 ? NEG_INF : -INFINITY);
            mq = fmaxf(mq, eq[t]);
        }
        #pragma unroll
        for (int off = 32; off >= 1; off >>= 1) mq = fmaxf(mq, __shfl_xor(mq, off));
        float sq = 0.f;
        #pragma unroll
        for (int t = 0; t < 4; ++t) {
            int j = tid + 64 * t;
            float pe = __expf(eq[t] - mq);
            sq += pe;
            if (j < 200) p0[j] = pe;
        }
        #pragma unroll
        for (int off = 32; off >= 1; off >>= 1) sq += __shfl_xor(sq, off);
        if (tid == 0) sumq_s = sq;
    }
    __syncthreads();
    if (tid < 32) {
        float acc = 0.f;
        for (int j = 0; j < 200; ++j) acc += p0[j] * Ys[j][4 + tid];
        hqt[tid] = acc / sumq_s;
    }
    __syncthreads();
    if (tid < 2) {
        float v = 0.f;
        #pragma unroll
        for (int f = 0; f < 32; ++f) v += hqt[f] * w2l[f * 2 + tid];
        out[204800 + (size_t)b * 2 + tid] = v > 0.f ? v : expm1f(v);
    }
}

// ---------------------------------------------------------------------------
extern "C" void kernel_launch(void* const* d_in, const int* in_sizes, int n_in,
                              void* d_out, int out_size, void* d_ws, size_t ws_size,
                              hipStream_t stream) {
    const float* feat   = (const float*)d_in[0];   // [256,200,768]
    const int*   adj    = (const int*)  d_in[1];   // [256,200,200]
    const float* Wh     = (const float*)d_in[2];   // [8,768,32]
    const float* ah     = (const float*)d_in[3];   // [8,64,1]
    const float* W_sent = (const float*)d_in[4];   // [256,2]
    const float* a_sent = (const float*)d_in[5];   // [4,1]
    const float* W_para = (const float*)d_in[6];   // [256,2]
    const float* a_para = (const float*)d_in[7];   // [4,1]
    const float* W_qt   = (const float*)d_in[8];   // [256,32]
    const float* a_qt   = (const float*)d_in[9];   // [64,1]
    const float* W2     = (const float*)d_in[10];  // [32,2]
    const float* bng    = (const float*)d_in[11];
    const float* bnb    = (const float*)d_in[12];
    const float* bnm    = (const float*)d_in[13];
    const float* bnv    = (const float*)d_in[14];

    float* H = (float*)d_ws;                 // [51200,256] -> becomes x in place
    float* Y = H + (size_t)51200 * 256;      // [51200,36]
    float* out = (float*)d_out;

    dim3 g1(800, 4);
    k_gemm1<<<g1, 256, 0, stream>>>(feat, Wh, H);
    k_attn1<<<2048, 256, 0, stream>>>(H, adj, ah, bng, bnb, bnm, bnv);
    k_gemm2<<<800, 256, 0, stream>>>(H, W_sent, W_para, W_qt, Y);
    k_attn2<<<256, 256, 0, stream>>>(Y, adj, a_sent, a_para, a_qt, W2, out);
}

// Round 2
// 1051.072 us; speedup vs baseline: 2.4237x; 2.4237x over previous
//
#include <hip/hip_runtime.h>
#include <hip/hip_bf16.h>

#define ALPHA   0.3f
#define NEG_INF (-9e15f)
#define BN_EPS  1e-5f

// ---------------------------------------------------------------------------
// K1: H[51200,256] = feat[51200,768] @ Wcat[768,256]
//     Wcat[k, h*32+f] = Wh[h,k,f]   (8 heads fused as column blocks)
// f32 tiled GEMM: 64x64 tile, BK=16, 256 threads, 4x4 micro-tile.
// ---------------------------------------------------------------------------
__global__ __launch_bounds__(256) void k_gemm1(const float* __restrict__ A,
                                               const float* __restrict__ Wh,
                                               float* __restrict__ H)
{
    __shared__ float As[16][68];   // [k][m], stride 68 keeps float4 16B-aligned
    __shared__ float Bs[16][68];   // [k][n]
    const int tid = threadIdx.x;
    const int tx = tid & 15, ty = tid >> 4;
    const size_t m0 = (size_t)blockIdx.x * 64;
    const int n0 = blockIdx.y * 64;
    const int arow = tid >> 2;          // 0..63
    const int ak4  = (tid & 3) * 4;     // 0,4,8,12
    float acc[4][4] = {};

    for (int kt = 0; kt < 768; kt += 16) {
        __syncthreads();
        { // A tile: 64 rows x 16 k, one float4 per thread (coalesced)
            const float4 a4 = *(const float4*)&A[(m0 + arow) * 768 + kt + ak4];
            As[ak4+0][arow] = a4.x; As[ak4+1][arow] = a4.y;
            As[ak4+2][arow] = a4.z; As[ak4+3][arow] = a4.w;
        }
        #pragma unroll
        for (int i = 0; i < 4; ++i) { // B tile: 16 k x 64 cols
            int l = tid + 256 * i;
            int k = l >> 6, c = l & 63;
            int col = n0 + c;
            Bs[k][c] = Wh[((size_t)(col >> 5) * 768 + kt + k) * 32 + (col & 31)];
        }
        __syncthreads();
        #pragma unroll
        for (int k = 0; k < 16; ++k) {
            float4 a4 = *(const float4*)&As[k][ty * 4];
            float4 b4 = *(const float4*)&Bs[k][tx * 4];
            float av[4] = {a4.x, a4.y, a4.z, a4.w};
            float bv[4] = {b4.x, b4.y, b4.z, b4.w};
            #pragma unroll
            for (int i = 0; i < 4; ++i)
                #pragma unroll
                for (int j = 0; j < 4; ++j)
                    acc[i][j] += av[i] * bv[j];
        }
    }
    #pragma unroll
    for (int i = 0; i < 4; ++i) {
        float4 v = make_float4(acc[i][0], acc[i][1], acc[i][2], acc[i][3]);
        *(float4*)&H[(m0 + ty * 4 + i) * 256 + n0 + tx * 4] = v;
    }
}

// ---------------------------------------------------------------------------
// K2: per (b, head): s1/s2, masked-softmax attention, out = att@H, elu, BN.
// Writes x in place over H (block owns its 32-col slice; H tile cached in LDS).
// ---------------------------------------------------------------------------
__global__ __launch_bounds__(256) void k_attn1(float* __restrict__ H,
    const int* __restrict__ adj, const float* __restrict__ ah,
    const float* __restrict__ bng, const float* __restrict__ bnb,
    const float* __restrict__ bnm, const float* __restrict__ bnv)
{
    __shared__ float HsT[32][208];      // transposed head tile, 16B-aligned rows
    __shared__ float s1[200], s2[200];
    __shared__ float av[64];
    __shared__ float p[8][200];         // exp-weights for an 8-row chunk
    __shared__ float rsum[8];
    const int tid  = threadIdx.x;
    const int b    = blockIdx.x >> 3;
    const int head = blockIdx.x & 7;
    float* Hb = H + (size_t)b * 200 * 256 + head * 32;
    const int* adjb = adj + (size_t)b * 200 * 200;

    for (int idx = tid; idx < 6400; idx += 256) {
        int n = idx >> 5, f = idx & 31;
        HsT[f][n] = Hb[n * 256 + f];
    }
    if (tid < 64) av[tid] = ah[head * 64 + tid];
    __syncthreads();

    if (tid < 200) {
        float v1 = 0.f, v2 = 0.f;
        #pragma unroll
        for (int f = 0; f < 32; ++f) {
            float h = HsT[f][tid];
            v1 += h * av[f];
            v2 += h * av[32 + f];
        }
        s1[tid] = v1; s2[tid] = v2;
    }
    __syncthreads();

    const int il   = tid >> 5;   // 0..7: row within chunk (half-wave per row)
    const int lane = tid & 31;
    const int fcol = tid & 31;

    for (int i0 = 0; i0 < 200; i0 += 8) {
        const int i = i0 + il;
        // ---- step 1: masked scores, row max, exp, row sum ----
        float m = -INFINITY;
        float vbuf[7];
        const float s1i = s1[i];
        #pragma unroll
        for (int t = 0; t < 7; ++t) {
            int j = lane + 32 * t;
            float v = -INFINITY;
            if (j < 200) {
                float e = s1i + s2[j];
                e = e >= 0.f ? e : ALPHA * e;
                v = (adjb[i * 200 + j] > 0) ? e : NEG_INF;
            }
            vbuf[t] = v;
            m = fmaxf(m, v);
        }
        #pragma unroll
        for (int off = 16; off >= 1; off >>= 1) m = fmaxf(m, __shfl_xor(m, off));
        float s = 0.f;
        #pragma unroll
        for (int t = 0; t < 7; ++t) {
            int j = lane + 32 * t;
            float pe = __expf(vbuf[t] - m);   // -INF lanes -> 0
            if (j < 200) p[il][j] = pe;
            s += pe;
        }
        #pragma unroll
        for (int off = 16; off >= 1; off >>= 1) s += __shfl_xor(s, off);
        if (lane == 0) rsum[il] = s;
        __syncthreads();
        // ---- step 2: out[i][f] = (sum_j p*H[j][f]) / sum; elu; BN ----
        float acc = 0.f;
        for (int j = 0; j < 200; j += 4) {
            float4 pv = *(const float4*)&p[il][j];
            float4 hv = *(const float4*)&HsT[fcol][j];
            acc += pv.x * hv.x + pv.y * hv.y + pv.z * hv.z + pv.w * hv.w;
        }
        float o = acc / rsum[il];
        o = o > 0.f ? o : expm1f(o);                       // elu
        float inv = bng[i] * rsqrtf(bnv[i] + BN_EPS);      // BN (channel = node)
        o = (o - bnm[i]) * inv + bnb[i];
        Hb[i * 256 + fcol] = o;                            // in-place x
        __syncthreads();
    }
}

// ---------------------------------------------------------------------------
// K3: Y[51200,36] = x[51200,256] @ [W_sent | W_para | W_qt]
// Col group g (9 cols) lives at 16B-aligned 12-float slot in LDS; inner loop
// kept at unroll-4 to stop LLVM from fully unrolling and spilling (round-1
// pathology: VGPR=256, 1.9 GB scratch traffic, 1530 us).
// ---------------------------------------------------------------------------
__global__ __launch_bounds__(256) void k_gemm2(const float* __restrict__ X,
    const float* __restrict__ Ws, const float* __restrict__ Wp,
    const float* __restrict__ Wq, float* __restrict__ Y)
{
    __shared__ float Wl[256][48];   // [k][12*g + c], c<9 used, pads never read
    __shared__ float XsT[64][68];   // [k][row]
    const int tid = threadIdx.x;
    {   // stage weights (once): thread tid = row k
        const int k = tid;
        // col order: [sent0, sent1, para0, para1, qt0..qt31] -> slot 12*(c/9)+c%9
        #pragma unroll
        for (int c = 0; c < 36; ++c) {
            float v;
            if      (c == 0) v = Ws[k * 2 + 0];
            else if (c == 1) v = Ws[k * 2 + 1];
            else if (c == 2) v = Wp[k * 2 + 0];
            else if (c == 3) v = Wp[k * 2 + 1];
            else             v = Wq[k * 32 + (c - 4)];
            Wl[k][12 * (c / 9) + (c % 9)] = v;
        }
    }
    const int r  = tid & 63;        // row within tile (wave-contiguous)
    const int cg = tid >> 6;        // col group 0..3 (uniform per wave)
    const size_t row0 = (size_t)blockIdx.x * 64;
    float acc[9] = {};

    for (int kt = 0; kt < 256; kt += 64) {
        __syncthreads();
        #pragma unroll
        for (int i = 0; i < 4; ++i) {      // 64x64 X tile, transposed into LDS
            int l = tid + 256 * i;
            int row = l >> 4;
            int k4 = (l & 15) * 4;
            const float4 x4 = *(const float4*)&X[(row0 + row) * 256 + kt + k4];
            XsT[k4 + 0][row] = x4.x; XsT[k4 + 1][row] = x4.y;
            XsT[k4 + 2][row] = x4.z; XsT[k4 + 3][row] = x4.w;
        }
        __syncthreads();
        #pragma unroll 4
        for (int k = 0; k < 64; ++k) {
            const float xv = XsT[k][r];
            const float4 w0 = *(const float4*)&Wl[kt + k][12 * cg + 0];
            const float4 w1 = *(const float4*)&Wl[kt + k][12 * cg + 4];
            const float  w2 = Wl[kt + k][12 * cg + 8];
            acc[0] += xv * w0.x; acc[1] += xv * w0.y;
            acc[2] += xv * w0.z; acc[3] += xv * w0.w;
            acc[4] += xv * w1.x; acc[5] += xv * w1.y;
            acc[6] += xv * w1.z; acc[7] += xv * w1.w;
            acc[8] += xv * w2;
        }
    }
    float* yr = Y + (row0 + r) * 36 + cg * 9;
    #pragma unroll
    for (int c = 0; c < 9; ++c) yr[c] = acc[c];
}

// ---------------------------------------------------------------------------
// K4: per b: 2nd-layer attention for sent (+sigmoid) and para (+elu) on all
// rows, and qt (row 0 only) -> elu(h_qt @ W2).
// ---------------------------------------------------------------------------
__global__ __launch_bounds__(256) void k_attn2(const float* __restrict__ Y,
    const int* __restrict__ adj, const float* __restrict__ a_s,
    const float* __restrict__ a_p, const float* __restrict__ a_q,
    const float* __restrict__ W2, float* __restrict__ out)
{
    __shared__ float Ys[200][37];
    __shared__ float s1s[200], s2s[200], p1s[200], p2s[200], sq2[200];
    __shared__ float p0[200];
    __shared__ float hqt[32];
    __shared__ float sumq_s;
    __shared__ float asl[4], apl[4], aql[64], w2l[64];
    const int tid = threadIdx.x;
    const int b   = blockIdx.x;
    const float* Yb = Y + (size_t)b * 7200;
    const int* adjb = adj + (size_t)b * 200 * 200;

    for (int idx = tid; idx < 7200; idx += 256) {
        int j = idx / 36;
        int c = idx - j * 36;
        Ys[j][c] = Yb[idx];
    }
    if (tid < 4)  { asl[tid] = a_s[tid]; apl[tid] = a_p[tid]; }
    if (tid < 64) { aql[tid] = a_q[tid]; w2l[tid] = W2[tid]; }
    __syncthreads();

    if (tid < 200) {
        int j = tid;
        s1s[j] = Ys[j][0] * asl[0] + Ys[j][1] * asl[1];
        s2s[j] = Ys[j][0] * asl[2] + Ys[j][1] * asl[3];
        p1s[j] = Ys[j][2] * apl[0] + Ys[j][3] * apl[1];
        p2s[j] = Ys[j][2] * apl[2] + Ys[j][3] * apl[3];
        float a = 0.f;
        #pragma unroll
        for (int f = 0; f < 32; ++f) a += Ys[j][4 + f] * aql[32 + f];
        sq2[j] = a;
    }
    __syncthreads();

    const int w = tid >> 6, lane = tid & 63;
    for (int i = w; i < 200; i += 4) {   // one wave per row
        const float s1i = s1s[i], p1i = p1s[i];
        float ms = -INFINITY, mp = -INFINITY;
        float es[4], ep[4];
        #pragma unroll
        for (int t = 0; t < 4; ++t) {
            int j = lane + 64 * t;
            int jj = j < 200 ? j : 0;
            int a = (j < 200) ? adjb[i * 200 + j] : 0;
            float e1 = s1i + s2s[jj]; e1 = e1 >= 0.f ? e1 : ALPHA * e1;
            float e2 = p1i + p2s[jj]; e2 = e2 >= 0.f ? e2 : ALPHA * e2;
            es[t] = (a > 0) ? e1 : (j < 200 ? NEG_INF : -INFINITY);
            ep[t] = (a > 0) ? e2 : (j < 200 ? NEG_INF : -INFINITY);
            ms = fmaxf(ms, es[t]); mp = fmaxf(mp, ep[t]);
        }
        #pragma unroll
        for (int off = 32; off >= 1; off >>= 1) {
            ms = fmaxf(ms, __shfl_xor(ms, off));
            mp = fmaxf(mp, __shfl_xor(mp, off));
        }
        float ss = 0.f, sp = 0.f, os0 = 0.f, os1 = 0.f, op0 = 0.f, op1 = 0.f;
        #pragma unroll
        for (int t = 0; t < 4; ++t) {
            int j = lane + 64 * t;
            int jj = j < 200 ? j : 0;
            float pes = __expf(es[t] - ms);
            float pep = __expf(ep[t] - mp);
            ss += pes; sp += pep;
            os0 += pes * Ys[jj][0]; os1 += pes * Ys[jj][1];
            op0 += pep * Ys[jj][2]; op1 += pep * Ys[jj][3];
        }
        #pragma unroll
        for (int off = 32; off >= 1; off >>= 1) {
            ss  += __shfl_xor(ss, off);  sp  += __shfl_xor(sp, off);
            os0 += __shfl_xor(os0, off); os1 += __shfl_xor(os1, off);
            op0 += __shfl_xor(op0, off); op1 += __shfl_xor(op1, off);
        }
        if (lane == 0) {
            float v0 = os0 / ss, v1 = os1 / ss;
            out[((size_t)b * 200 + i) * 2 + 0] = 1.f / (1.f + __expf(-v0));
            out[((size_t)b * 200 + i) * 2 + 1] = 1.f / (1.f + __expf(-v1));
            float q0 = op0 / sp, q1 = op1 / sp;
            out[102400 + ((size_t)b * 200 + i) * 2 + 0] = q0 > 0.f ? q0 : expm1f(q0);
            out[102400 + ((size_t)b * 200 + i) * 2 + 1] = q1 > 0.f ? q1 : expm1f(q1);
        }
    }

    // ---- qtype head: attention row 0 only ----
    if (tid < 64) {
        float s1q = 0.f;
        #pragma unroll
        for (int f = 0; f < 32; ++f) s1q += Ys[0][4 + f] * aql[f];
        float mq = -INFINITY;
        float eq[4];
        #pragma unroll
        for (int t = 0; t < 4; ++t) {
            int j = tid + 64 * t;
            int jj = j < 200 ? j : 0;
            int a = (j < 200) ? adjb[j] : 0;
            float e = s1q + sq2[jj]; e = e >= 0.f ? e : ALPHA * e;
            eq[t] = (a > 0) ? e : (j < 200 ? NEG_INF : -INFINITY);
            mq = fmaxf(mq, eq[t]);
        }
        #pragma unroll
        for (int off = 32; off >= 1; off >>= 1) mq = fmaxf(mq, __shfl_xor(mq, off));
        float sq = 0.f;
        #pragma unroll
        for (int t = 0; t < 4; ++t) {
            int j = tid + 64 * t;
            float pe = __expf(eq[t] - mq);
            sq += pe;
            if (j < 200) p0[j] = pe;
        }
        #pragma unroll
        for (int off = 32; off >= 1; off >>= 1) sq += __shfl_xor(sq, off);
        if (tid == 0) sumq_s = sq;
    }
    __syncthreads();
    if (tid < 32) {
        float acc = 0.f;
        for (int j = 0; j < 200; ++j) acc += p0[j] * Ys[j][4 + tid];
        hqt[tid] = acc / sumq_s;
    }
    __syncthreads();
    if (tid < 2) {
        float v = 0.f;
        #pragma unroll
        for (int f = 0; f < 32; ++f) v += hqt[f] * w2l[f * 2 + tid];
        out[204800 + (size_t)b * 2 + tid] = v > 0.f ? v : expm1f(v);
    }
}

// ---------------------------------------------------------------------------
extern "C" void kernel_launch(void* const* d_in, const int* in_sizes, int n_in,
                              void* d_out, int out_size, void* d_ws, size_t ws_size,
                              hipStream_t stream) {
    const float* feat   = (const float*)d_in[0];   // [256,200,768]
    const int*   adj    = (const int*)  d_in[1];   // [256,200,200]
    const float* Wh     = (const float*)d_in[2];   // [8,768,32]
    const float* ah     = (const float*)d_in[3];   // [8,64,1]
    const float* W_sent = (const float*)d_in[4];   // [256,2]
    const float* a_sent = (const float*)d_in[5];   // [4,1]
    const float* W_para = (const float*)d_in[6];   // [256,2]
    const float* a_para = (const float*)d_in[7];   // [4,1]
    const float* W_qt   = (const float*)d_in[8];   // [256,32]
    const float* a_qt   = (const float*)d_in[9];   // [64,1]
    const float* W2     = (const float*)d_in[10];  // [32,2]
    const float* bng    = (const float*)d_in[11];
    const float* bnb    = (const float*)d_in[12];
    const float* bnm    = (const float*)d_in[13];
    const float* bnv    = (const float*)d_in[14];

    float* H = (float*)d_ws;                 // [51200,256] -> becomes x in place
    float* Y = H + (size_t)51200 * 256;      // [51200,36]
    float* out = (float*)d_out;

    dim3 g1(800, 4);
    k_gemm1<<<g1, 256, 0, stream>>>(feat, Wh, H);
    k_attn1<<<2048, 256, 0, stream>>>(H, adj, ah, bng, bnb, bnm, bnv);
    k_gemm2<<<800, 256, 0, stream>>>(H, W_sent, W_para, W_qt, Y);
    k_attn2<<<256, 256, 0, stream>>>(Y, adj, a_sent, a_para, a_qt, W2, out);
}

// Round 4
// 763.714 us; speedup vs baseline: 3.3357x; 1.3763x over previous
//
#include <hip/hip_runtime.h>
#include <hip/hip_bf16.h>

#define ALPHA   0.3f
#define NEG_INF (-9e15f)
#define BN_EPS  1e-5f

typedef _Float16 f16x8 __attribute__((ext_vector_type(8)));
typedef float    f32x4 __attribute__((ext_vector_type(4)));

// ---------------------------------------------------------------------------
// K1: H[51200,256] = feat[51200,768] @ Wcat[768,256]
//     Wcat[k, h*32+f] = Wh[h,k,f]   (8 heads fused as column blocks)
// f32 tiled GEMM: 64x64 tile, BK=16, 256 threads, 4x4 micro-tile.
// ---------------------------------------------------------------------------
__global__ __launch_bounds__(256) void k_gemm1(const float* __restrict__ A,
                                               const float* __restrict__ Wh,
                                               float* __restrict__ H)
{
    __shared__ float As[16][68];   // [k][m], stride 68 keeps float4 16B-aligned
    __shared__ float Bs[16][68];   // [k][n]
    const int tid = threadIdx.x;
    const int tx = tid & 15, ty = tid >> 4;
    const size_t m0 = (size_t)blockIdx.x * 64;
    const int n0 = blockIdx.y * 64;
    const int arow = tid >> 2;          // 0..63
    const int ak4  = (tid & 3) * 4;     // 0,4,8,12
    float acc[4][4] = {};

    for (int kt = 0; kt < 768; kt += 16) {
        __syncthreads();
        { // A tile: 64 rows x 16 k, one float4 per thread (coalesced)
            const float4 a4 = *(const float4*)&A[(m0 + arow) * 768 + kt + ak4];
            As[ak4+0][arow] = a4.x; As[ak4+1][arow] = a4.y;
            As[ak4+2][arow] = a4.z; As[ak4+3][arow] = a4.w;
        }
        #pragma unroll
        for (int i = 0; i < 4; ++i) { // B tile: 16 k x 64 cols
            int l = tid + 256 * i;
            int k = l >> 6, c = l & 63;
            int col = n0 + c;
            Bs[k][c] = Wh[((size_t)(col >> 5) * 768 + kt + k) * 32 + (col & 31)];
        }
        __syncthreads();
        #pragma unroll
        for (int k = 0; k < 16; ++k) {
            float4 a4 = *(const float4*)&As[k][ty * 4];
            float4 b4 = *(const float4*)&Bs[k][tx * 4];
            float av[4] = {a4.x, a4.y, a4.z, a4.w};
            float bv[4] = {b4.x, b4.y, b4.z, b4.w};
            #pragma unroll
            for (int i = 0; i < 4; ++i)
                #pragma unroll
                for (int j = 0; j < 4; ++j)
                    acc[i][j] += av[i] * bv[j];
        }
    }
    #pragma unroll
    for (int i = 0; i < 4; ++i) {
        float4 v = make_float4(acc[i][0], acc[i][1], acc[i][2], acc[i][3]);
        *(float4*)&H[(m0 + ty * 4 + i) * 256 + n0 + tx * 4] = v;
    }
}

// ---------------------------------------------------------------------------
// K2: per (b, head): s1/s2, masked softmax, out = att@H via f16 MFMA, elu, BN.
// R3 failed with bf16 fragments (absmax 2.28): 8-bit mantissa on H/s1/s2
// perturbs softmax scores ~3%, amplified by layer-2 logit tails (+-35).
// Fix: fp16 fragments (11-bit mantissa; |h|<~30, p in [0,1] -> in range) and
// s1/s2 computed from f32 global H. LDS footprint unchanged (~45KB, 3 blk/CU).
// ---------------------------------------------------------------------------
__global__ __launch_bounds__(256) void k_attn1(float* __restrict__ H,
    const int* __restrict__ adj, const float* __restrict__ ah,
    const float* __restrict__ bng, const float* __restrict__ bnb,
    const float* __restrict__ bnm, const float* __restrict__ bnv)
{
    __shared__ _Float16 HsT[32][224];   // [f][j] f16 (B^T layout), rows 448B
    __shared__ _Float16 Pb[64][224];    // exp-weights for a 64-row chunk (A layout)
    __shared__ float s1[200], s2[200];
    __shared__ float av[64];
    __shared__ float rinv[64];
    const int tid  = threadIdx.x;
    const int b    = blockIdx.x >> 3;
    const int head = blockIdx.x & 7;
    float* Hb = H + (size_t)b * 200 * 256 + head * 32;
    const int* adjb = adj + (size_t)b * 200 * 200;

    // stage H slice (coalesced read) -> f16 transposed; zero K-pads
    for (int idx = tid; idx < 6400; idx += 256) {
        int n = idx >> 5, f = idx & 31;
        HsT[f][n] = (_Float16)Hb[n * 256 + f];
    }
    for (int idx = tid; idx < 32 * 24; idx += 256) {
        int f = idx / 24, c = 200 + idx % 24;
        HsT[f][c] = (_Float16)0.f;
    }
    for (int idx = tid; idx < 64 * 24; idx += 256) {
        int r = idx / 24, c = 200 + idx % 24;
        Pb[r][c] = (_Float16)0.f;             // written once, never overwritten
    }
    if (tid < 64) av[tid] = ah[head * 64 + tid];
    __syncthreads();

    // s1/s2 from f32 H (not the f16-rounded copy): scores drive softmax and
    // must stay accurate (see R3 post-mortem).
    if (tid < 200) {
        float v1 = 0.f, v2 = 0.f;
        #pragma unroll
        for (int f = 0; f < 32; f += 4) {
            const float4 h4 = *(const float4*)&Hb[tid * 256 + f];
            v1 += h4.x * av[f]      + h4.y * av[f + 1]
                + h4.z * av[f + 2]  + h4.w * av[f + 3];
            v2 += h4.x * av[32 + f]     + h4.y * av[32 + f + 1]
                + h4.z * av[32 + f + 2] + h4.w * av[32 + f + 3];
        }
        s1[tid] = v1; s2[tid] = v2;
    }
    __syncthreads();

    const int il     = tid >> 5;   // 0..7 (half-wave per row in step 1)
    const int lane32 = tid & 31;
    const int w      = tid >> 6;   // wave id 0..3
    const int lane   = tid & 63;
    const int r16    = lane & 15;
    const int q      = lane >> 4;

    for (int c0 = 0; c0 < 200; c0 += 64) {
        const int nrows = (200 - c0) < 64 ? (200 - c0) : 64;
        // ---- step 1: masked scores -> softmax weights (f16) + 1/rowsum ----
        for (int pass = 0; pass < (nrows >> 3); ++pass) {
            const int ilocal = pass * 8 + il;
            const int i = c0 + ilocal;
            float m = -INFINITY;
            float vbuf[7];
            const float s1i = s1[i];
            #pragma unroll
            for (int t = 0; t < 7; ++t) {
                int j = lane32 + 32 * t;
                float v = -INFINITY;
                if (j < 200) {
                    float e = s1i + s2[j];
                    e = e >= 0.f ? e : ALPHA * e;
                    v = (adjb[i * 200 + j] > 0) ? e : NEG_INF;
                }
                vbuf[t] = v;
                m = fmaxf(m, v);
            }
            #pragma unroll
            for (int off = 16; off >= 1; off >>= 1) m = fmaxf(m, __shfl_xor(m, off));
            float s = 0.f;
            #pragma unroll
            for (int t = 0; t < 7; ++t) {
                int j = lane32 + 32 * t;
                float pe = __expf(vbuf[t] - m);   // -INF lanes -> 0
                if (j < 200) Pb[ilocal][j] = (_Float16)pe;
                s += pe;
            }
            #pragma unroll
            for (int off = 16; off >= 1; off >>= 1) s += __shfl_xor(s, off);
            if (lane32 == 0) rinv[ilocal] = 1.f / s;
        }
        __syncthreads();
        // ---- step 2: O[nrows,32] = P @ H via 16x16x32 f16 MFMA ----
        const int mtiles = (nrows + 15) >> 4;
        for (int t = w; t < mtiles * 2; t += 4) {
            const int m0 = (t >> 1) * 16;
            const int f0 = (t & 1) * 16;
            f32x4 acc = {0.f, 0.f, 0.f, 0.f};
            #pragma unroll
            for (int k0 = 0; k0 < 224; k0 += 32) {
                f16x8 a  = *(const f16x8*)&Pb [m0 + r16][k0 + q * 8];
                f16x8 bb = *(const f16x8*)&HsT[f0 + r16][k0 + q * 8];
                acc = __builtin_amdgcn_mfma_f32_16x16x32_f16(a, bb, acc, 0, 0, 0);
            }
            #pragma unroll
            for (int r = 0; r < 4; ++r) {
                const int ilocal = m0 + q * 4 + r;   // D row = m
                const int i = c0 + ilocal;
                if (i < 200 && ilocal < nrows) {
                    float o = acc[r] * rinv[ilocal];
                    o = o > 0.f ? o : expm1f(o);                    // elu
                    float inv = bng[i] * rsqrtf(bnv[i] + BN_EPS);   // BN (ch = node)
                    o = (o - bnm[i]) * inv + bnb[i];
                    Hb[i * 256 + f0 + r16] = o;                     // D col = n = f
                }
            }
        }
        __syncthreads();
    }
}

// ---------------------------------------------------------------------------
// K3: Y[51200,36] = x[51200,256] @ [W_sent | W_para | W_qt]
// Col group g (9 cols) lives at 16B-aligned 12-float slot in LDS; inner loop
// kept at unroll-4 to stop LLVM from fully unrolling and spilling (round-1
// pathology: VGPR=256, 1.9 GB scratch traffic, 1530 us).
// ---------------------------------------------------------------------------
__global__ __launch_bounds__(256) void k_gemm2(const float* __restrict__ X,
    const float* __restrict__ Ws, const float* __restrict__ Wp,
    const float* __restrict__ Wq, float* __restrict__ Y)
{
    __shared__ float Wl[256][48];   // [k][12*g + c], c<9 used, pads never read
    __shared__ float XsT[64][68];   // [k][row]
    const int tid = threadIdx.x;
    {   // stage weights (once): thread tid = row k
        const int k = tid;
        #pragma unroll
        for (int c = 0; c < 36; ++c) {
            float v;
            if      (c == 0) v = Ws[k * 2 + 0];
            else if (c == 1) v = Ws[k * 2 + 1];
            else if (c == 2) v = Wp[k * 2 + 0];
            else if (c == 3) v = Wp[k * 2 + 1];
            else             v = Wq[k * 32 + (c - 4)];
            Wl[k][12 * (c / 9) + (c % 9)] = v;
        }
    }
    const int r  = tid & 63;        // row within tile (wave-contiguous)
    const int cg = tid >> 6;        // col group 0..3 (uniform per wave)
    const size_t row0 = (size_t)blockIdx.x * 64;
    float acc[9] = {};

    for (int kt = 0; kt < 256; kt += 64) {
        __syncthreads();
        #pragma unroll
        for (int i = 0; i < 4; ++i) {      // 64x64 X tile, transposed into LDS
            int l = tid + 256 * i;
            int row = l >> 4;
            int k4 = (l & 15) * 4;
            const float4 x4 = *(const float4*)&X[(row0 + row) * 256 + kt + k4];
            XsT[k4 + 0][row] = x4.x; XsT[k4 + 1][row] = x4.y;
            XsT[k4 + 2][row] = x4.z; XsT[k4 + 3][row] = x4.w;
        }
        __syncthreads();
        #pragma unroll 4
        for (int k = 0; k < 64; ++k) {
            const float xv = XsT[k][r];
            const float4 w0 = *(const float4*)&Wl[kt + k][12 * cg + 0];
            const float4 w1 = *(const float4*)&Wl[kt + k][12 * cg + 4];
            const float  w2 = Wl[kt + k][12 * cg + 8];
            acc[0] += xv * w0.x; acc[1] += xv * w0.y;
            acc[2] += xv * w0.z; acc[3] += xv * w0.w;
            acc[4] += xv * w1.x; acc[5] += xv * w1.y;
            acc[6] += xv * w1.z; acc[7] += xv * w1.w;
            acc[8] += xv * w2;
        }
    }
    float* yr = Y + (row0 + r) * 36 + cg * 9;
    #pragma unroll
    for (int c = 0; c < 9; ++c) yr[c] = acc[c];
}

// ---------------------------------------------------------------------------
// K4: per b: 2nd-layer attention for sent (+sigmoid) and para (+elu) on all
// rows, and qt (row 0 only) -> elu(h_qt @ W2).
// ---------------------------------------------------------------------------
__global__ __launch_bounds__(256) void k_attn2(const float* __restrict__ Y,
    const int* __restrict__ adj, const float* __restrict__ a_s,
    const float* __restrict__ a_p, const float* __restrict__ a_q,
    const float* __restrict__ W2, float* __restrict__ out)
{
    __shared__ float Ys[200][37];
    __shared__ float s1s[200], s2s[200], p1s[200], p2s[200], sq2[200];
    __shared__ float p0[200];
    __shared__ float hqt[32];
    __shared__ float sumq_s;
    __shared__ float asl[4], apl[4], aql[64], w2l[64];
    const int tid = threadIdx.x;
    const int b   = blockIdx.x;
    const float* Yb = Y + (size_t)b * 7200;
    const int* adjb = adj + (size_t)b * 200 * 200;

    for (int idx = tid; idx < 7200; idx += 256) {
        int j = idx / 36;
        int c = idx - j * 36;
        Ys[j][c] = Yb[idx];
    }
    if (tid < 4)  { asl[tid] = a_s[tid]; apl[tid] = a_p[tid]; }
    if (tid < 64) { aql[tid] = a_q[tid]; w2l[tid] = W2[tid]; }
    __syncthreads();

    if (tid < 200) {
        int j = tid;
        s1s[j] = Ys[j][0] * asl[0] + Ys[j][1] * asl[1];
        s2s[j] = Ys[j][0] * asl[2] + Ys[j][1] * asl[3];
        p1s[j] = Ys[j][2] * apl[0] + Ys[j][3] * apl[1];
        p2s[j] = Ys[j][2] * apl[2] + Ys[j][3] * apl[3];
        float a = 0.f;
        #pragma unroll
        for (int f = 0; f < 32; ++f) a += Ys[j][4 + f] * aql[32 + f];
        sq2[j] = a;
    }
    __syncthreads();

    const int w = tid >> 6, lane = tid & 63;
    for (int i = w; i < 200; i += 4) {   // one wave per row
        const float s1i = s1s[i], p1i = p1s[i];
        float ms = -INFINITY, mp = -INFINITY;
        float es[4], ep[4];
        #pragma unroll
        for (int t = 0; t < 4; ++t) {
            int j = lane + 64 * t;
            int jj = j < 200 ? j : 0;
            int a = (j < 200) ? adjb[i * 200 + j] : 0;
            float e1 = s1i + s2s[jj]; e1 = e1 >= 0.f ? e1 : ALPHA * e1;
            float e2 = p1i + p2s[jj]; e2 = e2 >= 0.f ? e2 : ALPHA * e2;
            es[t] = (a > 0) ? e1 : (j < 200 ? NEG_INF : -INFINITY);
            ep[t] = (a > 0) ? e2 : (j < 200 ? NEG_INF : -INFINITY);
            ms = fmaxf(ms, es[t]); mp = fmaxf(mp, ep[t]);
        }
        #pragma unroll
        for (int off = 32; off >= 1; off >>= 1) {
            ms = fmaxf(ms, __shfl_xor(ms, off));
            mp = fmaxf(mp, __shfl_xor(mp, off));
        }
        float ss = 0.f, sp = 0.f, os0 = 0.f, os1 = 0.f, op0 = 0.f, op1 = 0.f;
        #pragma unroll
        for (int t = 0; t < 4; ++t) {
            int j = lane + 64 * t;
            int jj = j < 200 ? j : 0;
            float pes = __expf(es[t] - ms);
            float pep = __expf(ep[t] - mp);
            ss += pes; sp += pep;
            os0 += pes * Ys[jj][0]; os1 += pes * Ys[jj][1];
            op0 += pep * Ys[jj][2]; op1 += pep * Ys[jj][3];
        }
        #pragma unroll
        for (int off = 32; off >= 1; off >>= 1) {
            ss  += __shfl_xor(ss, off);  sp  += __shfl_xor(sp, off);
            os0 += __shfl_xor(os0, off); os1 += __shfl_xor(os1, off);
            op0 += __shfl_xor(op0, off); op1 += __shfl_xor(op1, off);
        }
        if (lane == 0) {
            float v0 = os0 / ss, v1 = os1 / ss;
            out[((size_t)b * 200 + i) * 2 + 0] = 1.f / (1.f + __expf(-v0));
            out[((size_t)b * 200 + i) * 2 + 1] = 1.f / (1.f + __expf(-v1));
            float q0 = op0 / sp, q1 = op1 / sp;
            out[102400 + ((size_t)b * 200 + i) * 2 + 0] = q0 > 0.f ? q0 : expm1f(q0);
            out[102400 + ((size_t)b * 200 + i) * 2 + 1] = q1 > 0.f ? q1 : expm1f(q1);
        }
    }

    // ---- qtype head: attention row 0 only ----
    if (tid < 64) {
        float s1q = 0.f;
        #pragma unroll
        for (int f = 0; f < 32; ++f) s1q += Ys[0][4 + f] * aql[f];
        float mq = -INFINITY;
        float eq[4];
        #pragma unroll
        for (int t = 0; t < 4; ++t) {
            int j = tid + 64 * t;
            int jj = j < 200 ? j : 0;
            int a = (j < 200) ? adjb[j] : 0;
            float e = s1q + sq2[jj]; e = e >= 0.f ? e : ALPHA * e;
            eq[t] = (a > 0) ? e : (j < 200 ? NEG_INF : -INFINITY);
            mq = fmaxf(mq, eq[t]);
        }
        #pragma unroll
        for (int off = 32; off >= 1; off >>= 1) mq = fmaxf(mq, __shfl_xor(mq, off));
        float sq = 0.f;
        #pragma unroll
        for (int t = 0; t < 4; ++t) {
            int j = tid + 64 * t;
            float pe = __expf(eq[t] - mq);
            sq += pe;
            if (j < 200) p0[j] = pe;
        }
        #pragma unroll
        for (int off = 32; off >= 1; off >>= 1) sq += __shfl_xor(sq, off);
        if (tid == 0) sumq_s = sq;
    }
    __syncthreads();
    if (tid < 32) {
        float acc = 0.f;
        for (int j = 0; j < 200; ++j) acc += p0[j] * Ys[j][4 + tid];
        hqt[tid] = acc / sumq_s;
    }
    __syncthreads();
    if (tid < 2) {
        float v = 0.f;
        #pragma unroll
        for (int f = 0; f < 32; ++f) v += hqt[f] * w2l[f * 2 + tid];
        out[204800 + (size_t)b * 2 + tid] = v > 0.f ? v : expm1f(v);
    }
}

// ---------------------------------------------------------------------------
extern "C" void kernel_launch(void* const* d_in, const int* in_sizes, int n_in,
                              void* d_out, int out_size, void* d_ws, size_t ws_size,
                              hipStream_t stream) {
    const float* feat   = (const float*)d_in[0];   // [256,200,768]
    const int*   adj    = (const int*)  d_in[1];   // [256,200,200]
    const float* Wh     = (const float*)d_in[2];   // [8,768,32]
    const float* ah     = (const float*)d_in[3];   // [8,64,1]
    const float* W_sent = (const float*)d_in[4];   // [256,2]
    const float* a_sent = (const float*)d_in[5];   // [4,1]
    const float* W_para = (const float*)d_in[6];   // [256,2]
    const float* a_para = (const float*)d_in[7];   // [4,1]
    const float* W_qt   = (const float*)d_in[8];   // [256,32]
    const float* a_qt   = (const float*)d_in[9];   // [64,1]
    const float* W2     = (const float*)d_in[10];  // [32,2]
    const float* bng    = (const float*)d_in[11];
    const float* bnb    = (const float*)d_in[12];
    const float* bnm    = (const float*)d_in[13];
    const float* bnv    = (const float*)d_in[14];

    float* H = (float*)d_ws;                 // [51200,256] -> becomes x in place
    float* Y = H + (size_t)51200 * 256;      // [51200,36]
    float* out = (float*)d_out;

    dim3 g1(800, 4);
    k_gemm1<<<g1, 256, 0, stream>>>(feat, Wh, H);
    k_attn1<<<2048, 256, 0, stream>>>(H, adj, ah, bng, bnb, bnm, bnv);
    k_gemm2<<<800, 256, 0, stream>>>(H, W_sent, W_para, W_qt, Y);
    k_attn2<<<256, 256, 0, stream>>>(Y, adj, a_sent, a_para, a_qt, W2, out);
}

// Round 5
// 597.940 us; speedup vs baseline: 4.2605x; 1.2772x over previous
//
#include <hip/hip_runtime.h>
#include <hip/hip_bf16.h>

#define ALPHA   0.3f
#define NEG_INF (-9e15f)
#define BN_EPS  1e-5f

typedef _Float16 f16x4 __attribute__((ext_vector_type(4)));
typedef _Float16 f16x8 __attribute__((ext_vector_type(8)));
typedef float    f32x4 __attribute__((ext_vector_type(4)));

// ---------------------------------------------------------------------------
// K0: pack Wh[8,768,32] (f32) -> WcatT[256][768] (f16), WcatT[n][k] = Wcat[k,n]
// (B^T layout for the MFMA GEMM). 786KB read, ~2us.
// ---------------------------------------------------------------------------
__global__ __launch_bounds__(256) void k_wcat(const float* __restrict__ Wh,
                                              _Float16* __restrict__ WT)
{
    const int o = blockIdx.x * 256 + threadIdx.x;   // < 196608
    const int n = o / 768, k = o - n * 768;
    WT[o] = (_Float16)Wh[((n >> 5) * 768 + k) * 32 + (n & 31)];
}

// ---------------------------------------------------------------------------
// K1: H[51200,256] = feat @ Wcat via f16 MFMA.
// R4: f32-VALU version was compute-bound (285us, VALUBusy=67%, MfmaUtil=0).
// Tile 64Mx256N, BK=64, 4 waves (each 64x64 = 4x4 16x16 tiles). feat converted
// f32->f16 inline into Af (rows padded 64->72 f16: b128 frag-read start banks
// = 4*(r16+q) mod 32 -> optimal 8 accesses/bank). M-only grid: feat read once.
// f32 accumulate; precision budget ~0.08 on final logits (see R3/R4 notes).
// ---------------------------------------------------------------------------
__global__ __launch_bounds__(256) void k_gemm1(const float* __restrict__ A,
                                               const _Float16* __restrict__ WT,
                                               float* __restrict__ H)
{
    __shared__ _Float16 Af[64][72];    // [m][k]
    __shared__ _Float16 Bf[256][72];   // [n][k]
    const int tid  = threadIdx.x;
    const int wv   = tid >> 6;
    const int lane = tid & 63;
    const int r16  = lane & 15, q = lane >> 4;
    const size_t m_blk = (size_t)blockIdx.x * 64;
    const int wn = wv * 64;
    const int arow = tid >> 2, akb = (tid & 3) * 16;
    f32x4 acc[4][4] = {};   // [mi][ni]

    for (int kt = 0; kt < 768; kt += 64) {
        __syncthreads();
        #pragma unroll
        for (int p = 0; p < 4; ++p) {   // A: 64 rows x 64 k, f32 -> f16
            const float4 a4 = *(const float4*)&A[(m_blk + arow) * 768 + kt + akb + p * 4];
            f16x4 h4 = { (_Float16)a4.x, (_Float16)a4.y, (_Float16)a4.z, (_Float16)a4.w };
            *(f16x4*)&Af[arow][akb + p * 4] = h4;
        }
        #pragma unroll
        for (int p = 0; p < 8; ++p) {   // B: row n = tid, k 0..63 (f16 in global)
            f16x8 w8 = *(const f16x8*)&WT[tid * 768 + kt + p * 8];
            *(f16x8*)&Bf[tid][p * 8] = w8;
        }
        __syncthreads();
        #pragma unroll
        for (int kc = 0; kc < 64; kc += 32) {
            f16x8 af[4], bf[4];
            #pragma unroll
            for (int i = 0; i < 4; ++i)
                af[i] = *(const f16x8*)&Af[i * 16 + r16][kc + q * 8];
            #pragma unroll
            for (int j = 0; j < 4; ++j)
                bf[j] = *(const f16x8*)&Bf[wn + j * 16 + r16][kc + q * 8];
            #pragma unroll
            for (int i = 0; i < 4; ++i)
                #pragma unroll
                for (int j = 0; j < 4; ++j)
                    acc[i][j] = __builtin_amdgcn_mfma_f32_16x16x32_f16(
                        af[i], bf[j], acc[i][j], 0, 0, 0);
        }
    }
    #pragma unroll
    for (int i = 0; i < 4; ++i)
        #pragma unroll
        for (int j = 0; j < 4; ++j)
            #pragma unroll
            for (int r = 0; r < 4; ++r) {
                const int m = i * 16 + q * 4 + r;       // D row
                const int n = wn + j * 16 + r16;        // D col
                H[(m_blk + m) * 256 + n] = acc[i][j][r];
            }
}

// ---------------------------------------------------------------------------
// K2: per (b, head): s1/s2, masked softmax, out = att@H via f16 MFMA, elu, BN.
// R3 failed with bf16 fragments (absmax 2.28): 8-bit mantissa on H/s1/s2
// perturbs softmax scores ~3%, amplified by layer-2 logit tails (+-35).
// Fix: fp16 fragments and s1/s2 computed from f32 global H.
// ---------------------------------------------------------------------------
__global__ __launch_bounds__(256) void k_attn1(float* __restrict__ H,
    const int* __restrict__ adj, const float* __restrict__ ah,
    const float* __restrict__ bng, const float* __restrict__ bnb,
    const float* __restrict__ bnm, const float* __restrict__ bnv)
{
    __shared__ _Float16 HsT[32][224];   // [f][j] f16 (B^T layout), rows 448B
    __shared__ _Float16 Pb[64][224];    // exp-weights for a 64-row chunk (A layout)
    __shared__ float s1[200], s2[200];
    __shared__ float av[64];
    __shared__ float rinv[64];
    const int tid  = threadIdx.x;
    const int b    = blockIdx.x >> 3;
    const int head = blockIdx.x & 7;
    float* Hb = H + (size_t)b * 200 * 256 + head * 32;
    const int* adjb = adj + (size_t)b * 200 * 200;

    // stage H slice (coalesced read) -> f16 transposed; zero K-pads
    for (int idx = tid; idx < 6400; idx += 256) {
        int n = idx >> 5, f = idx & 31;
        HsT[f][n] = (_Float16)Hb[n * 256 + f];
    }
    for (int idx = tid; idx < 32 * 24; idx += 256) {
        int f = idx / 24, c = 200 + idx % 24;
        HsT[f][c] = (_Float16)0.f;
    }
    for (int idx = tid; idx < 64 * 24; idx += 256) {
        int r = idx / 24, c = 200 + idx % 24;
        Pb[r][c] = (_Float16)0.f;             // written once, never overwritten
    }
    if (tid < 64) av[tid] = ah[head * 64 + tid];
    __syncthreads();

    // s1/s2 from f32 H (not the f16-rounded copy): scores drive softmax and
    // must stay accurate (see R3 post-mortem).
    if (tid < 200) {
        float v1 = 0.f, v2 = 0.f;
        #pragma unroll
        for (int f = 0; f < 32; f += 4) {
            const float4 h4 = *(const float4*)&Hb[tid * 256 + f];
            v1 += h4.x * av[f]      + h4.y * av[f + 1]
                + h4.z * av[f + 2]  + h4.w * av[f + 3];
            v2 += h4.x * av[32 + f]     + h4.y * av[32 + f + 1]
                + h4.z * av[32 + f + 2] + h4.w * av[32 + f + 3];
        }
        s1[tid] = v1; s2[tid] = v2;
    }
    __syncthreads();

    const int il     = tid >> 5;   // 0..7 (half-wave per row in step 1)
    const int lane32 = tid & 31;
    const int w      = tid >> 6;   // wave id 0..3
    const int lane   = tid & 63;
    const int r16    = lane & 15;
    const int q      = lane >> 4;

    for (int c0 = 0; c0 < 200; c0 += 64) {
        const int nrows = (200 - c0) < 64 ? (200 - c0) : 64;
        // ---- step 1: masked scores -> softmax weights (f16) + 1/rowsum ----
        for (int pass = 0; pass < (nrows >> 3); ++pass) {
            const int ilocal = pass * 8 + il;
            const int i = c0 + ilocal;
            float m = -INFINITY;
            float vbuf[7];
            const float s1i = s1[i];
            #pragma unroll
            for (int t = 0; t < 7; ++t) {
                int j = lane32 + 32 * t;
                float v = -INFINITY;
                if (j < 200) {
                    float e = s1i + s2[j];
                    e = e >= 0.f ? e : ALPHA * e;
                    v = (adjb[i * 200 + j] > 0) ? e : NEG_INF;
                }
                vbuf[t] = v;
                m = fmaxf(m, v);
            }
            #pragma unroll
            for (int off = 16; off >= 1; off >>= 1) m = fmaxf(m, __shfl_xor(m, off));
            float s = 0.f;
            #pragma unroll
            for (int t = 0; t < 7; ++t) {
                int j = lane32 + 32 * t;
                float pe = __expf(vbuf[t] - m);   // -INF lanes -> 0
                if (j < 200) Pb[ilocal][j] = (_Float16)pe;
                s += pe;
            }
            #pragma unroll
            for (int off = 16; off >= 1; off >>= 1) s += __shfl_xor(s, off);
            if (lane32 == 0) rinv[ilocal] = 1.f / s;
        }
        __syncthreads();
        // ---- step 2: O[nrows,32] = P @ H via 16x16x32 f16 MFMA ----
        const int mtiles = (nrows + 15) >> 4;
        for (int t = w; t < mtiles * 2; t += 4) {
            const int m0 = (t >> 1) * 16;
            const int f0 = (t & 1) * 16;
            f32x4 acc = {0.f, 0.f, 0.f, 0.f};
            #pragma unroll
            for (int k0 = 0; k0 < 224; k0 += 32) {
                f16x8 a  = *(const f16x8*)&Pb [m0 + r16][k0 + q * 8];
                f16x8 bb = *(const f16x8*)&HsT[f0 + r16][k0 + q * 8];
                acc = __builtin_amdgcn_mfma_f32_16x16x32_f16(a, bb, acc, 0, 0, 0);
            }
            #pragma unroll
            for (int r = 0; r < 4; ++r) {
                const int ilocal = m0 + q * 4 + r;   // D row = m
                const int i = c0 + ilocal;
                if (i < 200 && ilocal < nrows) {
                    float o = acc[r] * rinv[ilocal];
                    o = o > 0.f ? o : expm1f(o);                    // elu
                    float inv = bng[i] * rsqrtf(bnv[i] + BN_EPS);   // BN (ch = node)
                    o = (o - bnm[i]) * inv + bnb[i];
                    Hb[i * 256 + f0 + r16] = o;                     // D col = n = f
                }
            }
        }
        __syncthreads();
    }
}

// ---------------------------------------------------------------------------
// K3: Y[51200,36] = x[51200,256] @ [W_sent | W_para | W_qt]
// Col group g (9 cols) lives at 16B-aligned 12-float slot in LDS; inner loop
// kept at unroll-4 to stop LLVM from fully unrolling and spilling (round-1
// pathology: VGPR=256, 1.9 GB scratch traffic, 1530 us).
// ---------------------------------------------------------------------------
__global__ __launch_bounds__(256) void k_gemm2(const float* __restrict__ X,
    const float* __restrict__ Ws, const float* __restrict__ Wp,
    const float* __restrict__ Wq, float* __restrict__ Y)
{
    __shared__ float Wl[256][48];   // [k][12*g + c], c<9 used, pads never read
    __shared__ float XsT[64][68];   // [k][row]
    const int tid = threadIdx.x;
    {   // stage weights (once): thread tid = row k
        const int k = tid;
        #pragma unroll
        for (int c = 0; c < 36; ++c) {
            float v;
            if      (c == 0) v = Ws[k * 2 + 0];
            else if (c == 1) v = Ws[k * 2 + 1];
            else if (c == 2) v = Wp[k * 2 + 0];
            else if (c == 3) v = Wp[k * 2 + 1];
            else             v = Wq[k * 32 + (c - 4)];
            Wl[k][12 * (c / 9) + (c % 9)] = v;
        }
    }
    const int r  = tid & 63;        // row within tile (wave-contiguous)
    const int cg = tid >> 6;        // col group 0..3 (uniform per wave)
    const size_t row0 = (size_t)blockIdx.x * 64;
    float acc[9] = {};

    for (int kt = 0; kt < 256; kt += 64) {
        __syncthreads();
        #pragma unroll
        for (int i = 0; i < 4; ++i) {      // 64x64 X tile, transposed into LDS
            int l = tid + 256 * i;
            int row = l >> 4;
            int k4 = (l & 15) * 4;
            const float4 x4 = *(const float4*)&X[(row0 + row) * 256 + kt + k4];
            XsT[k4 + 0][row] = x4.x; XsT[k4 + 1][row] = x4.y;
            XsT[k4 + 2][row] = x4.z; XsT[k4 + 3][row] = x4.w;
        }
        __syncthreads();
        #pragma unroll 4
        for (int k = 0; k < 64; ++k) {
            const float xv = XsT[k][r];
            const float4 w0 = *(const float4*)&Wl[kt + k][12 * cg + 0];
            const float4 w1 = *(const float4*)&Wl[kt + k][12 * cg + 4];
            const float  w2 = Wl[kt + k][12 * cg + 8];
            acc[0] += xv * w0.x; acc[1] += xv * w0.y;
            acc[2] += xv * w0.z; acc[3] += xv * w0.w;
            acc[4] += xv * w1.x; acc[5] += xv * w1.y;
            acc[6] += xv * w1.z; acc[7] += xv * w1.w;
            acc[8] += xv * w2;
        }
    }
    float* yr = Y + (row0 + r) * 36 + cg * 9;
    #pragma unroll
    for (int c = 0; c < 9; ++c) yr[c] = acc[c];
}

// ---------------------------------------------------------------------------
// K4: per b: 2nd-layer attention for sent (+sigmoid) and para (+elu) on all
// rows, and qt (row 0 only) -> elu(h_qt @ W2).
// ---------------------------------------------------------------------------
__global__ __launch_bounds__(256) void k_attn2(const float* __restrict__ Y,
    const int* __restrict__ adj, const float* __restrict__ a_s,
    const float* __restrict__ a_p, const float* __restrict__ a_q,
    const float* __restrict__ W2, float* __restrict__ out)
{
    __shared__ float Ys[200][37];
    __shared__ float s1s[200], s2s[200], p1s[200], p2s[200], sq2[200];
    __shared__ float p0[200];
    __shared__ float hqt[32];
    __shared__ float sumq_s;
    __shared__ float asl[4], apl[4], aql[64], w2l[64];
    const int tid = threadIdx.x;
    const int b   = blockIdx.x;
    const float* Yb = Y + (size_t)b * 7200;
    const int* adjb = adj + (size_t)b * 200 * 200;

    for (int idx = tid; idx < 7200; idx += 256) {
        int j = idx / 36;
        int c = idx - j * 36;
        Ys[j][c] = Yb[idx];
    }
    if (tid < 4)  { asl[tid] = a_s[tid]; apl[tid] = a_p[tid]; }
    if (tid < 64) { aql[tid] = a_q[tid]; w2l[tid] = W2[tid]; }
    __syncthreads();

    if (tid < 200) {
        int j = tid;
        s1s[j] = Ys[j][0] * asl[0] + Ys[j][1] * asl[1];
        s2s[j] = Ys[j][0] * asl[2] + Ys[j][1] * asl[3];
        p1s[j] = Ys[j][2] * apl[0] + Ys[j][3] * apl[1];
        p2s[j] = Ys[j][2] * apl[2] + Ys[j][3] * apl[3];
        float a = 0.f;
        #pragma unroll
        for (int f = 0; f < 32; ++f) a += Ys[j][4 + f] * aql[32 + f];
        sq2[j] = a;
    }
    __syncthreads();

    const int w = tid >> 6, lane = tid & 63;
    for (int i = w; i < 200; i += 4) {   // one wave per row
        const float s1i = s1s[i], p1i = p1s[i];
        float ms = -INFINITY, mp = -INFINITY;
        float es[4], ep[4];
        #pragma unroll
        for (int t = 0; t < 4; ++t) {
            int j = lane + 64 * t;
            int jj = j < 200 ? j : 0;
            int a = (j < 200) ? adjb[i * 200 + j] : 0;
            float e1 = s1i + s2s[jj]; e1 = e1 >= 0.f ? e1 : ALPHA * e1;
            float e2 = p1i + p2s[jj]; e2 = e2 >= 0.f ? e2 : ALPHA * e2;
            es[t] = (a > 0) ? e1 : (j < 200 ? NEG_INF : -INFINITY);
            ep[t] = (a > 0) ? e2 : (j < 200 ? NEG_INF : -INFINITY);
            ms = fmaxf(ms, es[t]); mp = fmaxf(mp, ep[t]);
        }
        #pragma unroll
        for (int off = 32; off >= 1; off >>= 1) {
            ms = fmaxf(ms, __shfl_xor(ms, off));
            mp = fmaxf(mp, __shfl_xor(mp, off));
        }
        float ss = 0.f, sp = 0.f, os0 = 0.f, os1 = 0.f, op0 = 0.f, op1 = 0.f;
        #pragma unroll
        for (int t = 0; t < 4; ++t) {
            int j = lane + 64 * t;
            int jj = j < 200 ? j : 0;
            float pes = __expf(es[t] - ms);
            float pep = __expf(ep[t] - mp);
            ss += pes; sp += pep;
            os0 += pes * Ys[jj][0]; os1 += pes * Ys[jj][1];
            op0 += pep * Ys[jj][2]; op1 += pep * Ys[jj][3];
        }
        #pragma unroll
        for (int off = 32; off >= 1; off >>= 1) {
            ss  += __shfl_xor(ss, off);  sp  += __shfl_xor(sp, off);
            os0 += __shfl_xor(os0, off); os1 += __shfl_xor(os1, off);
            op0 += __shfl_xor(op0, off); op1 += __shfl_xor(op1, off);
        }
        if (lane == 0) {
            float v0 = os0 / ss, v1 = os1 / ss;
            out[((size_t)b * 200 + i) * 2 + 0] = 1.f / (1.f + __expf(-v0));
            out[((size_t)b * 200 + i) * 2 + 1] = 1.f / (1.f + __expf(-v1));
            float q0 = op0 / sp, q1 = op1 / sp;
            out[102400 + ((size_t)b * 200 + i) * 2 + 0] = q0 > 0.f ? q0 : expm1f(q0);
            out[102400 + ((size_t)b * 200 + i) * 2 + 1] = q1 > 0.f ? q1 : expm1f(q1);
        }
    }

    // ---- qtype head: attention row 0 only ----
    if (tid < 64) {
        float s1q = 0.f;
        #pragma unroll
        for (int f = 0; f < 32; ++f) s1q += Ys[0][4 + f] * aql[f];
        float mq = -INFINITY;
        float eq[4];
        #pragma unroll
        for (int t = 0; t < 4; ++t) {
            int j = tid + 64 * t;
            int jj = j < 200 ? j : 0;
            int a = (j < 200) ? adjb[j] : 0;
            float e = s1q + sq2[jj]; e = e >= 0.f ? e : ALPHA * e;
            eq[t] = (a > 0) ? e : (j < 200 ? NEG_INF : -INFINITY);
            mq = fmaxf(mq, eq[t]);
        }
        #pragma unroll
        for (int off = 32; off >= 1; off >>= 1) mq = fmaxf(mq, __shfl_xor(mq, off));
        float sq = 0.f;
        #pragma unroll
        for (int t = 0; t < 4; ++t) {
            int j = tid + 64 * t;
            float pe = __expf(eq[t] - mq);
            sq += pe;
            if (j < 200) p0[j] = pe;
        }
        #pragma unroll
        for (int off = 32; off >= 1; off >>= 1) sq += __shfl_xor(sq, off);
        if (tid == 0) sumq_s = sq;
    }
    __syncthreads();
    if (tid < 32) {
        float acc = 0.f;
        for (int j = 0; j < 200; ++j) acc += p0[j] * Ys[j][4 + tid];
        hqt[tid] = acc / sumq_s;
    }
    __syncthreads();
    if (tid < 2) {
        float v = 0.f;
        #pragma unroll
        for (int f = 0; f < 32; ++f) v += hqt[f] * w2l[f * 2 + tid];
        out[204800 + (size_t)b * 2 + tid] = v > 0.f ? v : expm1f(v);
    }
}

// ---------------------------------------------------------------------------
extern "C" void kernel_launch(void* const* d_in, const int* in_sizes, int n_in,
                              void* d_out, int out_size, void* d_ws, size_t ws_size,
                              hipStream_t stream) {
    const float* feat   = (const float*)d_in[0];   // [256,200,768]
    const int*   adj    = (const int*)  d_in[1];   // [256,200,200]
    const float* Wh     = (const float*)d_in[2];   // [8,768,32]
    const float* ah     = (const float*)d_in[3];   // [8,64,1]
    const float* W_sent = (const float*)d_in[4];   // [256,2]
    const float* a_sent = (const float*)d_in[5];   // [4,1]
    const float* W_para = (const float*)d_in[6];   // [256,2]
    const float* a_para = (const float*)d_in[7];   // [4,1]
    const float* W_qt   = (const float*)d_in[8];   // [256,32]
    const float* a_qt   = (const float*)d_in[9];   // [64,1]
    const float* W2     = (const float*)d_in[10];  // [32,2]
    const float* bng    = (const float*)d_in[11];
    const float* bnb    = (const float*)d_in[12];
    const float* bnm    = (const float*)d_in[13];
    const float* bnv    = (const float*)d_in[14];

    float* H = (float*)d_ws;                 // [51200,256] -> becomes x in place
    float* Y = H + (size_t)51200 * 256;      // [51200,36]
    _Float16* WT = (_Float16*)(Y + (size_t)51200 * 36);  // [256,768] f16
    float* out = (float*)d_out;

    k_wcat<<<768, 256, 0, stream>>>(Wh, WT);
    k_gemm1<<<800, 256, 0, stream>>>(feat, WT, H);
    k_attn1<<<2048, 256, 0, stream>>>(H, adj, ah, bng, bnb, bnm, bnv);
    k_gemm2<<<800, 256, 0, stream>>>(H, W_sent, W_para, W_qt, Y);
    k_attn2<<<256, 256, 0, stream>>>(Y, adj, a_sent, a_para, a_qt, W2, out);
}